// Round 2
// baseline (493.222 us; speedup 1.0000x reference)
//
#include <hip/hip_runtime.h>
#include <hip/hip_bf16.h>

#define B_    4
#define CIN   64
#define COUT  64
#define KN    16
#define NPTS  32768

// ---------------------------------------------------------------------------
// Kernel 1: features [B][Cin][N] fp32 -> ft [B][N][Cin] bf16 (rounded).
// A neighbor column becomes one contiguous 128B (2-line) segment.
// ---------------------------------------------------------------------------
__global__ __launch_bounds__(256) void transpose_feat_kernel(
    const float* __restrict__ f, __hip_bfloat16* __restrict__ ft) {
  __shared__ float tile[64][65];            // +1 pad: conflict-free transpose
  const int b    = blockIdx.y;
  const int n0   = blockIdx.x * 64;
  const int lane = threadIdx.x & 63;
  const int g    = threadIdx.x >> 6;        // 0..3
  const float* src = f + (size_t)b * CIN * NPTS + n0;
#pragma unroll
  for (int cc = 0; cc < 16; ++cc)
    tile[cc * 4 + g][lane] = src[(size_t)(cc * 4 + g) * NPTS + lane];
  __syncthreads();
  __hip_bfloat16* dst = ft + ((size_t)b * NPTS + n0) * CIN;
  const int nrow = threadIdx.x >> 5;        // 0..7
  const int c2   = (threadIdx.x & 31) * 2;  // channel pair
#pragma unroll
  for (int pass = 0; pass < 8; ++pass) {
    const int n = pass * 8 + nrow;
    __hip_bfloat162 v = __float22bfloat162_rn(
        make_float2(tile[c2][n], tile[c2 + 1][n]));
    *(__hip_bfloat162*)&dst[(size_t)n * CIN + c2] = v;
  }
}

// ---------------------------------------------------------------------------
// Kernel 2: positions [B][3][N] -> pt [B][N][4] (xyz0, 16B aligned)
// ---------------------------------------------------------------------------
__global__ __launch_bounds__(256) void transpose_pos_kernel(
    const float* __restrict__ p, float4* __restrict__ pt) {
  const int b = blockIdx.y;
  const int n = blockIdx.x * 256 + threadIdx.x;
  const float* src = p + (size_t)b * 3 * NPTS;
  float4 v;
  v.x = src[n];
  v.y = src[NPTS + n];
  v.z = src[2 * NPTS + n];
  v.w = 0.f;
  pt[(size_t)b * NPTS + n] = v;
}

// ---------------------------------------------------------------------------
// Kernel 3: fused gather + k-contraction + 256->64 linear map.
// Block = 256 threads = 4 waves; each wave owns 16 points processed as two
// 8-point chunks (even points, then odd points) so the LDS T buffer is only
// 256 rows x 9 words = 9KB/wave -> 36KB/block -> 4 blocks/CU -> 16 waves/CU.
// Stride 9 (gcd(9,32)=1): conflict-free column writes.
// ---------------------------------------------------------------------------
__global__ __launch_bounds__(256) void flexconv_kernel(
    const __hip_bfloat16* __restrict__ ft,  // [B][N][64] bf16
    const float4* __restrict__ pt,          // [B][N]
    const int*    __restrict__ nb,          // [B][16][N]
    const float*  __restrict__ wt,          // [192][64] theta rows c'=d*64+c
    const float*  __restrict__ wb,          // [64][64]  bias-weight rows
    const float*  __restrict__ bias,        // [64]
    float*        __restrict__ out)         // [B][64][N]
{
  __shared__ float Tbuf[4 * 256 * 9];       // 36 KB
  const int wv   = threadIdx.x >> 6;
  const int lane = threadIdx.x & 63;
  float* T = Tbuf + wv * (256 * 9);

  const int b      = blockIdx.y;
  const int n_base = blockIdx.x * 64 + wv * 16;

  const unsigned short* fpk = (const unsigned short*)(ft + (size_t)b * NPTS * CIN);
  const float4* ptb = pt + (size_t)b * NPTS;
  const int*    nbb = nb + (size_t)b * KN * NPTS;

  const int oi = lane >> 3;   // output group 0..7 (8 outputs each)
  const int pi = lane & 7;    // point column 0..7

  float acc[8][2];
#pragma unroll
  for (int a = 0; a < 8; ++a) {
    const float bv = bias[oi * 8 + a];
    acc[a][0] = bv; acc[a][1] = bv;
  }

#pragma unroll
  for (int c = 0; c < 2; ++c) {             // chunk: even pts, then odd pts
    // ---- phase 1: T[c'][pc] for 8 points, lane = channel ----
#pragma unroll 2
    for (int pc = 0; pc < 8; ++pc) {
      const int n = n_base + pc * 2 + c;
      const float4 ctr = ptb[n];
      float fsum = 0.f, s0 = 0.f, s1 = 0.f, s2 = 0.f;
#pragma unroll
      for (int k = 0; k < KN; ++k) {
        const int idx = nbb[(size_t)k * NPTS + n];          // 1 line
        const unsigned short u = fpk[(size_t)idx * CIN + lane]; // 128B coalesced
        const float fv = __uint_as_float(((unsigned)u) << 16);
        const float4 q = ptb[idx];                          // 1-line broadcast
        fsum += fv;
        s0 += fv * (q.x - ctr.x);
        s1 += fv * (q.y - ctr.y);
        s2 += fv * (q.z - ctr.z);
      }
      T[(      lane) * 9 + pc] = s0;
      T[( 64 + lane) * 9 + pc] = s1;
      T[(128 + lane) * 9 + pc] = s2;
      T[(192 + lane) * 9 + pc] = fsum;
    }
    // wave-private LDS; same-wave ordering via lgkmcnt — no barrier needed.

    // ---- phase 2: acc[a][c] += sum_c' T[c'][pi] * W[c'][oi*8+a] ----
#pragma unroll 4
    for (int r = 0; r < 192; ++r) {
      const float t = T[r * 9 + pi];
      const float* wp = wt + (size_t)r * 64 + oi * 8;
      const float4 w0 = *(const float4*)wp;
      const float4 w1 = *(const float4*)(wp + 4);
      acc[0][c] += w0.x * t;  acc[1][c] += w0.y * t;
      acc[2][c] += w0.z * t;  acc[3][c] += w0.w * t;
      acc[4][c] += w1.x * t;  acc[5][c] += w1.y * t;
      acc[6][c] += w1.z * t;  acc[7][c] += w1.w * t;
    }
#pragma unroll 4
    for (int r = 0; r < 64; ++r) {
      const float t = T[(192 + r) * 9 + pi];
      const float* wp = wb + (size_t)r * 64 + oi * 8;
      const float4 w0 = *(const float4*)wp;
      const float4 w1 = *(const float4*)(wp + 4);
      acc[0][c] += w0.x * t;  acc[1][c] += w0.y * t;
      acc[2][c] += w0.z * t;  acc[3][c] += w0.w * t;
      acc[4][c] += w1.x * t;  acc[5][c] += w1.y * t;
      acc[6][c] += w1.z * t;  acc[7][c] += w1.w * t;
    }
  }

  // ---- epilogue: lane pi holds points n_base+2pi (c=0) and +2pi+1 (c=1) ----
  float* op = out + (size_t)b * COUT * NPTS + n_base + pi * 2;
#pragma unroll
  for (int a = 0; a < 8; ++a) {
    *(float2*)&op[(size_t)(oi * 8 + a) * NPTS] = make_float2(acc[a][0], acc[a][1]);
  }
}

// ---------------------------------------------------------------------------
extern "C" void kernel_launch(void* const* d_in, const int* in_sizes, int n_in,
                              void* d_out, int out_size, void* d_ws, size_t ws_size,
                              hipStream_t stream) {
  const float* features = (const float*)d_in[0];   // [B][64][N]
  const float* wt       = (const float*)d_in[1];   // [3][64][64]
  const float* wb       = (const float*)d_in[2];   // [64][64]
  const float* bias     = (const float*)d_in[3];   // [64]
  const int*   nb       = (const int*)  d_in[4];   // [B][16][N]
  const float* pos      = (const float*)d_in[5];   // [B][3][N]
  float* out = (float*)d_out;

  __hip_bfloat16* ftb = (__hip_bfloat16*)d_ws;                          // 16.8 MB
  float4* pt = (float4*)((char*)d_ws + (size_t)B_ * NPTS * CIN * 2);    // +2.1 MB

  dim3 gt(NPTS / 64, B_);
  transpose_feat_kernel<<<gt, 256, 0, stream>>>(features, ftb);
  dim3 gp(NPTS / 256, B_);
  transpose_pos_kernel<<<gp, 256, 0, stream>>>(pos, pt);
  dim3 gm(NPTS / 64, B_);
  flexconv_kernel<<<gm, 256, 0, stream>>>(ftb, pt, nb, wt, wb, bias, out);
}

// Round 3
// 264.516 us; speedup vs baseline: 1.8646x; 1.8646x over previous
//
#include <hip/hip_runtime.h>
#include <hip/hip_bf16.h>

#define B_    4
#define CIN   64
#define COUT  64
#define KN    16
#define NPTS  32768

typedef __attribute__((ext_vector_type(8))) short short8;
typedef __attribute__((ext_vector_type(4))) float f32x4;

// ---------------------------------------------------------------------------
// K1: features [B][64][N] f32 -> ft [B][N][64] bf16 (neighbor column = 128B)
// ---------------------------------------------------------------------------
__global__ __launch_bounds__(256) void transpose_feat_kernel(
    const float* __restrict__ f, __hip_bfloat16* __restrict__ ft) {
  __shared__ float tile[64][65];
  const int b    = blockIdx.y;
  const int n0   = blockIdx.x * 64;
  const int lane = threadIdx.x & 63;
  const int g    = threadIdx.x >> 6;
  const float* src = f + (size_t)b * CIN * NPTS + n0;
#pragma unroll
  for (int cc = 0; cc < 16; ++cc)
    tile[cc * 4 + g][lane] = src[(size_t)(cc * 4 + g) * NPTS + lane];
  __syncthreads();
  __hip_bfloat16* dst = ft + ((size_t)b * NPTS + n0) * CIN;
  const int nrow = threadIdx.x >> 5;
  const int c2   = (threadIdx.x & 31) * 2;
#pragma unroll
  for (int pass = 0; pass < 8; ++pass) {
    const int n = pass * 8 + nrow;
    __hip_bfloat162 v = __float22bfloat162_rn(
        make_float2(tile[c2][n], tile[c2 + 1][n]));
    *(__hip_bfloat162*)&dst[(size_t)n * CIN + c2] = v;
  }
}

// ---------------------------------------------------------------------------
// K2: positions [B][3][N] -> pt [B][N][4] float4
// ---------------------------------------------------------------------------
__global__ __launch_bounds__(256) void transpose_pos_kernel(
    const float* __restrict__ p, float4* __restrict__ pt) {
  const int b = blockIdx.y;
  const int n = blockIdx.x * 256 + threadIdx.x;
  const float* src = p + (size_t)b * 3 * NPTS;
  float4 v;
  v.x = src[n];
  v.y = src[NPTS + n];
  v.z = src[2 * NPTS + n];
  v.w = 0.f;
  pt[(size_t)b * NPTS + n] = v;
}

// ---------------------------------------------------------------------------
// K3: weights -> Wt [64 o][256 c'] bf16, with c' = c*4 + d  (d=3 -> wb row)
// ---------------------------------------------------------------------------
__global__ __launch_bounds__(256) void prep_w_kernel(
    const float* __restrict__ wt, const float* __restrict__ wb,
    __hip_bfloat16* __restrict__ Wt) {
  const int t  = blockIdx.x * 256 + threadIdx.x;   // o*256 + c'
  const int o  = t >> 8;
  const int cp = t & 255;
  const int c  = cp >> 2;
  const int d  = cp & 3;
  const float v = (d < 3) ? wt[((size_t)d * 64 + c) * 64 + o]
                          : wb[(size_t)c * 64 + o];
  Wt[t] = __float2bfloat16(v);
}

// ---------------------------------------------------------------------------
// K4: gather + k-contraction -> T [B][chunk_pts][256] bf16.
// No LDS. lane = channel. idx via readfirstlane -> SGPR gather bases.
// S = sum f*q - fsum*ctr.  T[n][c*4+{0,1,2,3}] = {s0,s1,s2,fsum}: one 8B
// nontemporal store per lane per point (keeps L2 for the gather tables).
// XCD swizzle: batch b -> XCDs {2b,2b+1} so gathers hit XCD-local L2.
// ---------------------------------------------------------------------------
__global__ __launch_bounds__(256) void gather_kernel(
    const __hip_bfloat16* __restrict__ ft,   // [B][N][64]
    const float4* __restrict__ pt,           // [B][N]
    const int*    __restrict__ nb,           // [B][16][N]
    __hip_bfloat16* __restrict__ T,          // [B][chunk_pts][256]
    int chunk_off, int chunk_pts)
{
  const int lane = threadIdx.x & 63;
  const int wv   = threadIdx.x >> 6;
  const int per_batch = chunk_pts >> 6;      // blocks per batch
  const int half_sz   = per_batch >> 1;
  const int xcd  = blockIdx.x & 7;
  const int b    = xcd >> 1;
  const int nblock = (xcd & 1) * half_sz + (blockIdx.x >> 3);
  int n_base = chunk_off + nblock * 64 + wv * 16;
  n_base = __builtin_amdgcn_readfirstlane(n_base);

  const unsigned short* fpk = (const unsigned short*)(ft + (size_t)b * NPTS * CIN);
  const float4* ptb = pt + (size_t)b * NPTS;
  const int*    nbb = nb + (size_t)b * KN * NPTS;
  unsigned short* Tb = (unsigned short*)T
      + ((size_t)b * chunk_pts + (size_t)(n_base - chunk_off)) * 256;

#pragma unroll 2
  for (int p = 0; p < 16; ++p) {
    const int n = n_base + p;
    const float4 ctr = ptb[n];
    float s0 = 0.f, s1 = 0.f, s2 = 0.f, fs = 0.f;
#pragma unroll
    for (int k = 0; k < KN; ++k) {
      const int idx = __builtin_amdgcn_readfirstlane(nbb[(size_t)k * NPTS + n]);
      const float4 q = ptb[idx];
      const unsigned short u = fpk[(size_t)idx * CIN + lane];
      const float fv = __uint_as_float((unsigned)u << 16);
      fs += fv;
      s0 += fv * q.x;
      s1 += fv * q.y;
      s2 += fv * q.z;
    }
    s0 -= fs * ctr.x; s1 -= fs * ctr.y; s2 -= fs * ctr.z;
    __hip_bfloat162 lo = __float22bfloat162_rn(make_float2(s0, s1));
    __hip_bfloat162 hi = __float22bfloat162_rn(make_float2(s2, fs));
    unsigned long long pk =
        ((unsigned long long)(*(unsigned*)&hi) << 32) | (*(unsigned*)&lo);
    __builtin_nontemporal_store(
        pk, (unsigned long long*)(Tb + (size_t)p * 256 + lane * 4));
  }
}

// ---------------------------------------------------------------------------
// K5: out[b][o][n] = sum_c' Wt[o][c'] * T[n][c'] + bias[o]   via MFMA bf16.
// Block = 4 waves; wave wv owns M-tile o in [wv*16, wv*16+16), 64 n-cols.
// A-frag: lane holds Wt[o = wv*16 + (lane&15)][kk*32 + (lane>>4)*8 + j].
// B-frag: lane holds T[n = n0+nt*16+(lane&15)][same k] -> contiguous 16B.
// D: col = lane&15 = n, row = (lane>>4)*4 + r = o-offset.
// ---------------------------------------------------------------------------
__global__ __launch_bounds__(256) void gemm_kernel(
    const __hip_bfloat16* __restrict__ T,    // [B][chunk_pts][256]
    const __hip_bfloat16* __restrict__ Wt,   // [64][256]
    const float* __restrict__ bias,          // [64]
    float* __restrict__ out,                 // [B][64][N]
    int chunk_off, int chunk_pts)
{
  const int lane = threadIdx.x & 63;
  const int wv   = threadIdx.x >> 6;
  const int b    = blockIdx.y;
  const int n0   = blockIdx.x * 64;          // within chunk
  const int col  = lane & 15;
  const int krow = lane >> 4;                // 0..3

  const unsigned short* wr =
      (const unsigned short*)Wt + ((size_t)(wv * 16 + col)) * 256 + krow * 8;
  short8 a[8];
#pragma unroll
  for (int kk = 0; kk < 8; ++kk) a[kk] = *(const short8*)(wr + kk * 32);

  const unsigned short* tb =
      (const unsigned short*)T + ((size_t)b * chunk_pts + n0) * 256 + krow * 8;

  f32x4 acc[4];
#pragma unroll
  for (int nt = 0; nt < 4; ++nt) acc[nt] = (f32x4){0.f, 0.f, 0.f, 0.f};

#pragma unroll
  for (int nt = 0; nt < 4; ++nt) {
    const unsigned short* tc = tb + (size_t)(nt * 16 + col) * 256;
#pragma unroll
    for (int kk = 0; kk < 8; ++kk) {
      short8 bf = *(const short8*)(tc + kk * 32);
      acc[nt] = __builtin_amdgcn_mfma_f32_16x16x32_bf16(a[kk], bf, acc[nt], 0, 0, 0);
    }
  }

  const float4 bv = *(const float4*)(bias + wv * 16 + krow * 4);
  float* ob = out + ((size_t)b * COUT + wv * 16 + krow * 4) * NPTS
                  + chunk_off + n0 + col;
#pragma unroll
  for (int r = 0; r < 4; ++r) {
    const float badd = (r == 0) ? bv.x : (r == 1) ? bv.y : (r == 2) ? bv.z : bv.w;
    float* orow = ob + (size_t)r * NPTS;
#pragma unroll
    for (int nt = 0; nt < 4; ++nt)
      orow[nt * 16] = acc[nt][r] + badd;
  }
}

// ---------------------------------------------------------------------------
extern "C" void kernel_launch(void* const* d_in, const int* in_sizes, int n_in,
                              void* d_out, int out_size, void* d_ws, size_t ws_size,
                              hipStream_t stream) {
  const float* features = (const float*)d_in[0];   // [B][64][N]
  const float* wtheta   = (const float*)d_in[1];   // [3][64][64]
  const float* wbias    = (const float*)d_in[2];   // [64][64]
  const float* bias     = (const float*)d_in[3];   // [64]
  const int*   nb       = (const int*)  d_in[4];   // [B][16][N]
  const float* pos      = (const float*)d_in[5];   // [B][3][N]
  float* out = (float*)d_out;

  char* ws = (char*)d_ws;
  __hip_bfloat16* ft = (__hip_bfloat16*)ws;                             // 16.78 MB
  float4*         pt = (float4*)(ws + 16777216);                        //  2.10 MB
  __hip_bfloat16* Wt = (__hip_bfloat16*)(ws + 16777216 + 2097152);      // 32 KB
  __hip_bfloat16* T  = (__hip_bfloat16*)(ws + 16777216 + 2097152 + 32768);

  // pick T chunking that fits the workspace (deterministic per ws_size)
  const size_t t_base  = 16777216 + 2097152 + 32768;
  const size_t t_avail = (ws_size > t_base) ? ws_size - t_base : 0;
  int nchunk = 1;
  while (nchunk < 16 &&
         (size_t)B_ * (NPTS / nchunk) * 256 * 2 > t_avail) nchunk <<= 1;
  const int chunk_pts = NPTS / nchunk;

  transpose_feat_kernel<<<dim3(NPTS / 64, B_), 256, 0, stream>>>(features, ft);
  transpose_pos_kernel<<<dim3(NPTS / 256, B_), 256, 0, stream>>>(pos, pt);
  prep_w_kernel<<<64, 256, 0, stream>>>(wtheta, wbias, Wt);

  for (int c = 0; c < nchunk; ++c) {
    const int off = c * chunk_pts;
    gather_kernel<<<B_ * (chunk_pts / 64), 256, 0, stream>>>(
        ft, pt, nb, T, off, chunk_pts);
    gemm_kernel<<<dim3(chunk_pts / 64, B_), 256, 0, stream>>>(
        T, Wt, bias, out, off, chunk_pts);
  }
}